// Round 5
// baseline (985.080 us; speedup 1.0000x reference)
//
#include <hip/hip_runtime.h>
#include <math.h>

#define NN 100000
#define NE 1000000
#define D 64
#define L 3
#define RVQ 3
#define CODES 16
#define BN_EPS 1e-5f
#define COMMIT_W 0.25f

#define GRID_A 2048   // blocks for bnstats kernel (fixed: partials + node mapping)

// ---------------- ws layout (in 4-byte units) ----------------
#define OFS_ROWPTR 0           // 100001 ints
#define OFS_CNT    100016      // 100000 ints
#define OFS_CURSOR 200032      // 100000 ints
#define OFS_BSUMS  300048      // 128 ints
#define OFS_BOFFS  300176      // 128 ints
#define OFS_STATS  300304      // 3*128 floats (sum[64],sumsq[64] per layer)
#define OFS_CSR    300800      // 1000000 ints
#define OFS_HA     1300800     // 6400000 floats
#define OFS_HB     7700800     // 6400000 floats
#define OFS_XLOC   14100800    // 6400000 floats
#define OFS_PART   20500800    // 2048*128 floats = 262144
// total = 20,762,944 * 4 B ~= 83 MB
// NOTE: the mean buffer now lives in d_out's pred region (scratch until
// k_head overwrites it at the very end) -- keeps ws footprint unchanged.

// ---------------- d_out layout (floats) ----------------
#define OUT_PRED   0
#define OUT_COMMIT (NN * D)                       // 6,400,000
#define OUT_IDS    (NN * D + 1)                   // 6,400,001
#define OUT_GNN    (NN * D + 1 + NN * (L * RVQ))  // 7,300,001

static __device__ __forceinline__ float waveSum(float v) {
    #pragma unroll
    for (int off = 32; off; off >>= 1) v += __shfl_xor(v, off, 64);
    return v;
}

// DPP quad-permute helpers: value from lane^1 / lane^2 within each quad.
static __device__ __forceinline__ float qxor1(float v) {
    return __int_as_float(__builtin_amdgcn_mov_dpp(__float_as_int(v), 0xB1, 0xF, 0xF, 1));
}
static __device__ __forceinline__ float qxor2(float v) {
    return __int_as_float(__builtin_amdgcn_mov_dpp(__float_as_int(v), 0x4E, 0xF, 0xF, 1));
}

// ---------------- CSR build ----------------
__global__ void k_count(const int* __restrict__ dst, int* __restrict__ cnt) {
    int e = blockIdx.x * blockDim.x + threadIdx.x;
    if (e < NE) atomicAdd(&cnt[dst[e]], 1);
}

#define SCAN_B 1024
__global__ void k_scan1(const int* __restrict__ cnt, int* __restrict__ rowptr,
                        int* __restrict__ bsums) {
    __shared__ int sm[SCAN_B];
    int t = threadIdx.x;
    int i = blockIdx.x * SCAN_B + t;
    int v = (i < NN) ? cnt[i] : 0;
    sm[t] = v;
    __syncthreads();
    for (int off = 1; off < SCAN_B; off <<= 1) {
        int add = (t >= off) ? sm[t - off] : 0;
        __syncthreads();
        sm[t] += add;
        __syncthreads();
    }
    if (i < NN) rowptr[i + 1] = sm[t];
    if (t == SCAN_B - 1) bsums[blockIdx.x] = sm[t];
}

__global__ void k_scan2(const int* __restrict__ bsums, int* __restrict__ boffs, int nb) {
    __shared__ int sm[SCAN_B];
    int t = threadIdx.x;
    int orig = (t < nb) ? bsums[t] : 0;
    sm[t] = orig;
    __syncthreads();
    for (int off = 1; off < SCAN_B; off <<= 1) {
        int add = (t >= off) ? sm[t - off] : 0;
        __syncthreads();
        sm[t] += add;
        __syncthreads();
    }
    if (t < nb) boffs[t] = sm[t] - orig;  // exclusive
}

__global__ void k_scan3(int* __restrict__ rowptr, const int* __restrict__ boffs) {
    int i = blockIdx.x * SCAN_B + threadIdx.x;
    if (i < NN) rowptr[i + 1] += boffs[blockIdx.x];
    if (i == 0) rowptr[0] = 0;
}

__global__ void k_cursor(const int* __restrict__ rowptr, int* __restrict__ cursor) {
    int i = blockIdx.x * blockDim.x + threadIdx.x;
    if (i < NN) cursor[i] = rowptr[i];
}

__global__ void k_fill(const int* __restrict__ src, const int* __restrict__ dst,
                       int* __restrict__ cursor, int* __restrict__ csr_src) {
    int e = blockIdx.x * blockDim.x + threadIdx.x;
    if (e < NE) {
        int p = atomicAdd(&cursor[dst[e]], 1);
        csr_src[p] = src[e];
    }
}

// Canonicalize row order so the neighbor-sum order is deterministic.
__global__ void k_sortrows(const int* __restrict__ rowptr, int* __restrict__ csr) {
    int n = blockIdx.x * blockDim.x + threadIdx.x;
    if (n >= NN) return;
    int r0 = rowptr[n], r1 = rowptr[n + 1];
    for (int i = r0 + 1; i < r1; ++i) {
        int v = csr[i];
        int j = i - 1;
        while (j >= r0 && csr[j] > v) { csr[j + 1] = csr[j]; --j; }
        csr[j + 1] = v;
    }
}

// ---------------- Gather: mean of neighbor rows -> mean_out ----------------
__global__ __launch_bounds__(256) void k_gather(
    const float* __restrict__ h, const int* __restrict__ rowptr,
    const int* __restrict__ csr_src, float* __restrict__ mean_out) {
    int t = threadIdx.x;
    int lane = t & 63, wid = t >> 6;
    int n = blockIdx.x * 4 + wid;
    if (n >= NN) return;

    int r0 = rowptr[n], r1 = rowptr[n + 1];
    float s = 0.f;
    for (int base = r0; base < r1; base += 64) {
        int last = r1 - 1;
        int ii = base + lane;
        int idx = csr_src[(ii <= last) ? ii : last];  // coalesced, clamped
        int m = r1 - base;
        if (m > 64) m = 64;
        int j = 0;
        for (; j + 8 <= m; j += 8) {
            int i0 = __shfl(idx, j + 0, 64), i1 = __shfl(idx, j + 1, 64);
            int i2 = __shfl(idx, j + 2, 64), i3 = __shfl(idx, j + 3, 64);
            int i4 = __shfl(idx, j + 4, 64), i5 = __shfl(idx, j + 5, 64);
            int i6 = __shfl(idx, j + 6, 64), i7 = __shfl(idx, j + 7, 64);
            float v0 = h[i0 * D + lane], v1 = h[i1 * D + lane];
            float v2 = h[i2 * D + lane], v3 = h[i3 * D + lane];
            float v4 = h[i4 * D + lane], v5 = h[i5 * D + lane];
            float v6 = h[i6 * D + lane], v7 = h[i7 * D + lane];
            s += v0; s += v1; s += v2; s += v3;
            s += v4; s += v5; s += v6; s += v7;
        }
        for (; j + 4 <= m; j += 4) {
            int i0 = __shfl(idx, j + 0, 64), i1 = __shfl(idx, j + 1, 64);
            int i2 = __shfl(idx, j + 2, 64), i3 = __shfl(idx, j + 3, 64);
            float v0 = h[i0 * D + lane], v1 = h[i1 * D + lane];
            float v2 = h[i2 * D + lane], v3 = h[i3 * D + lane];
            s += v0; s += v1; s += v2; s += v3;
        }
        for (; j < m; ++j) {
            int i0 = __shfl(idx, j, 64);
            s += h[i0 * D + lane];
        }
    }
    float deg = (float)(r1 - r0);
    mean_out[n * D + lane] = s / fmaxf(deg, 1.0f);
}

// ---------------- Matvec: SAGE transform + skip linear ----------------
// SGPR-broadcast version. lane = output channel (the original mapping ->
// waveSum butterfly and FMA chains are trivially bit-identical). Each wave
// owns 8 nodes; K-chunks of 16 keep only 48 weight floats + 24 accs live
// (~95 VGPR, capped 128 by launch_bounds -> no spill, unlike R4's 84+spill
// that wrote 75 MB of scratch). The activation rows are WAVE-UNIFORM
// (readfirstlane'd node index) reads from buffers never written by this
// kernel (mean lives in d_out's pred region) -> the compiler scalarizes
// them to s_load feeding v_fmac's SGPR operand: broadcast costs ZERO VALU
// and ZERO DS ops. (R4's ds_read_b128 broadcasts oversubscribed the
// per-CU DS pipe 4x: 16 useful bytes per ~10 DS cycles, while VALU is
// per-SIMD. SMEM is the broadcast pipe; DS is not.)
__global__ __launch_bounds__(256, 4) void k_matvec(
    const float* __restrict__ mean, const float* __restrict__ h,
    float* __restrict__ hp,
    const float* __restrict__ Wa, const float* __restrict__ ba,
    const float* __restrict__ Wr, const float* __restrict__ Wl,
    const float* __restrict__ bl) {
    int t = threadIdx.x, lane = t & 63, wid = t >> 6;
    int tb = (blockIdx.x * 4 + wid) * 8;             // 12500 waves exactly
    int nu = __builtin_amdgcn_readfirstlane(tb);     // force uniform base

    float bav = ba[lane], blv = bl[lane];

    float am[8], rm[8], lm[8];
    #pragma unroll
    for (int i = 0; i < 8; ++i) { am[i] = 0.f; rm[i] = 0.f; lm[i] = 0.f; }

    for (int c = 0; c < 4; ++c) {           // K chunks of 16
        // chunk weights: 48 per-lane coalesced dword loads (VMEM, L2-hot)
        float wa16[16], wr16[16], wl16[16];
        #pragma unroll
        for (int j = 0; j < 16; ++j) {
            wa16[j] = Wa[(c * 16 + j) * D + lane];
            wr16[j] = Wr[(c * 16 + j) * D + lane];
            wl16[j] = Wl[(c * 16 + j) * D + lane];
        }
        #pragma unroll
        for (int i = 0; i < 8; ++i) {
            // wave-uniform activation rows -> scalar loads (SGPR broadcast)
            const float4* mb = (const float4*)(mean + (size_t)(nu + i) * D + c * 16);
            const float4* hb = (const float4*)(h    + (size_t)(nu + i) * D + c * 16);
            #pragma unroll
            for (int qq = 0; qq < 4; ++qq) {
                float4 m4 = mb[qq];
                float4 h4 = hb[qq];
                am[i] += m4.x * wa16[4 * qq + 0];
                rm[i] += h4.x * wr16[4 * qq + 0];
                lm[i] += h4.x * wl16[4 * qq + 0];
                am[i] += m4.y * wa16[4 * qq + 1];
                rm[i] += h4.y * wr16[4 * qq + 1];
                lm[i] += h4.y * wl16[4 * qq + 1];
                am[i] += m4.z * wa16[4 * qq + 2];
                rm[i] += h4.z * wr16[4 * qq + 2];
                lm[i] += h4.z * wl16[4 * qq + 2];
                am[i] += m4.w * wa16[4 * qq + 3];
                rm[i] += h4.w * wr16[4 * qq + 3];
                lm[i] += h4.w * wl16[4 * qq + 3];
            }
        }
    }

    #pragma unroll
    for (int i = 0; i < 8; ++i) {
        float sage = am[i] + bav + rm[i];
        float ss = waveSum(sage * sage);
        float inv = 1.0f / (sqrtf(ss) + 1e-12f);
        float hpv = sage * inv + lm[i] + blv;
        hp[(size_t)(nu + i) * D + lane] = hpv;
    }
}

// BN stat partials over the finished hp buffer. Replicates the ORIGINAL
// k_matvec accumulation order exactly (same grid, same wave->node
// grid-stride, same reduce tree) -> stats are BIT-IDENTICAL; zero
// numerical risk to the VQ argmax ids.
__global__ __launch_bounds__(256) void k_bnstats(
    const float* __restrict__ hp, float* __restrict__ partials) {
    __shared__ float red[2][4][D];
    int t = threadIdx.x, lane = t & 63, wid = t >> 6;
    int wg = blockIdx.x * 4 + wid;
    const int wstep = GRID_A * 4;
    float accS = 0.f, accQ = 0.f;
    for (int n = wg; n < NN; n += wstep) {
        float hpv = hp[(size_t)n * D + lane];
        accS += hpv;
        accQ += hpv * hpv;
    }
    red[0][wid][lane] = accS;
    red[1][wid][lane] = accQ;
    __syncthreads();
    if (wid == 0) {
        float s0 = (red[0][0][lane] + red[0][1][lane]) + (red[0][2][lane] + red[0][3][lane]);
        float q0 = (red[1][0][lane] + red[1][1][lane]) + (red[1][2][lane] + red[1][3][lane]);
        partials[blockIdx.x * 128 + lane]      = s0;
        partials[blockIdx.x * 128 + 64 + lane] = q0;
    }
}

// Parallel deterministic reduction of BN stat partials.
__global__ __launch_bounds__(256) void k_red_stats(
    const float* __restrict__ part, float* __restrict__ stats) {
    __shared__ float sm[256];
    int c = blockIdx.x;      // 0..127
    int i = threadIdx.x;     // 0..255
    float s = 0.f;
    #pragma unroll
    for (int k = 0; k < 8; ++k)
        s += part[(size_t)(i * 8 + k) * 128 + c];
    sm[i] = s;
    __syncthreads();
    #pragma unroll
    for (int off = 128; off >= 1; off >>= 1) {
        if (i < off) sm[i] += sm[i + off];
        __syncthreads();
    }
    if (i == 0) stats[c] = sm[0];
}

// ---------------- Layer part B: BN + ReLU + x_local accumulate + residual VQ
// Quad-per-node scheme: residual in registers, DPP quad reduces, serial
// first-max argmax; bit-identical sims to the wave-per-node original.
#define CBSTRIDE 68
__global__ __launch_bounds__(256) void k_layer_b(
    float* __restrict__ hp,              // in: pre-BN h'; out: post-ReLU h
    const float* __restrict__ stats,
    const float* __restrict__ gamma, const float* __restrict__ beta,
    const float* __restrict__ cbs,       // [RVQ][CODES][D] for this layer
    float* __restrict__ x_local,
    float* __restrict__ ids_out,         // [NN][L*RVQ] region base
    int layer, float* __restrict__ commit, int first_layer) {
    __shared__ alignas(16) float scb[RVQ * CODES * CBSTRIDE];
    __shared__ alignas(16) float sscale[D];
    __shared__ alignas(16) float sshift[D];
    __shared__ float sred[4];
    int t = threadIdx.x, lane = t & 63, wid = t >> 6;

    // normalize codebook rows into LDS (identical math to before)
    for (int row = wid; row < RVQ * CODES; row += 4) {
        float v = cbs[row * D + lane];
        float ss = waveSum(v * v);
        scb[row * CBSTRIDE + lane] = v / (sqrtf(ss) + 1e-12f);
    }
    // BN scale/shift per channel
    if (t < D) {
        float mu = stats[t] * (1.0f / NN);
        float var = stats[64 + t] * (1.0f / NN) - mu * mu;
        float scale = rsqrtf(var + BN_EPS) * gamma[t];
        sscale[t] = scale;
        sshift[t] = beta[t] - mu * scale;
    }
    __syncthreads();

    int gid = blockIdx.x * 256 + t;
    int node = gid >> 2;      // one node per quad of lanes
    int part = t & 3;         // which 16-channel slice this lane owns
    float closs = 0.f;

    if (node < NN) {
        float res[16];
        size_t base = (size_t)node * D + part * 16;
        const float4* hr = (const float4*)(hp + base);
        float4* hw = (float4*)(hp + base);
        float4* xw = (float4*)(x_local + base);
        const float4* scp = (const float4*)(sscale + part * 16);
        const float4* shp = (const float4*)(sshift + part * 16);

        #pragma unroll
        for (int i = 0; i < 4; ++i) {
            float4 v = hr[i];
            float4 sc = scp[i], sh = shp[i];
            float4 hn;
            hn.x = fmaxf(v.x * sc.x + sh.x, 0.f);
            hn.y = fmaxf(v.y * sc.y + sh.y, 0.f);
            hn.z = fmaxf(v.z * sc.z + sh.z, 0.f);
            hn.w = fmaxf(v.w * sc.w + sh.w, 0.f);
            hw[i] = hn;
            if (first_layer) {
                xw[i] = hn;
            } else {
                float4 xl = xw[i];
                xl.x += hn.x; xl.y += hn.y; xl.z += hn.z; xl.w += hn.w;
                xw[i] = xl;
            }
            res[4 * i + 0] = hn.x; res[4 * i + 1] = hn.y;
            res[4 * i + 2] = hn.z; res[4 * i + 3] = hn.w;
        }

        int bis[RVQ];
        #pragma unroll
        for (int r = 0; r < RVQ; ++r) {
            float sims[CODES];
            #pragma unroll
            for (int j = 0; j < CODES; ++j) {
                const float* cr = &scb[(r * CODES + j) * CBSTRIDE + part * 16];
                float4 c0 = *(const float4*)(cr + 0);
                float4 c1 = *(const float4*)(cr + 4);
                float4 c2 = *(const float4*)(cr + 8);
                float4 c3 = *(const float4*)(cr + 12);
                float a = res[0] * c0.x;
                a += res[1] * c0.y;  a += res[2] * c0.z;  a += res[3] * c0.w;
                a += res[4] * c1.x;  a += res[5] * c1.y;  a += res[6] * c1.z;  a += res[7] * c1.w;
                a += res[8] * c2.x;  a += res[9] * c2.y;  a += res[10] * c2.z; a += res[11] * c2.w;
                a += res[12] * c3.x; a += res[13] * c3.y; a += res[14] * c3.z; a += res[15] * c3.w;
                float b = a + qxor1(a);
                sims[j] = b + qxor2(b);
            }
            float bv = sims[0];
            int bi = 0;
            #pragma unroll
            for (int j = 1; j < CODES; ++j)
                if (sims[j] > bv) { bv = sims[j]; bi = j; }

            const float* qr = &scb[(r * CODES + bi) * CBSTRIDE + part * 16];
            #pragma unroll
            for (int i = 0; i < 4; ++i) {
                float4 q = *(const float4*)(qr + 4 * i);
                float d0 = q.x - res[4 * i + 0]; closs += d0 * d0; res[4 * i + 0] = -d0;
                float d1 = q.y - res[4 * i + 1]; closs += d1 * d1; res[4 * i + 1] = -d1;
                float d2 = q.z - res[4 * i + 2]; closs += d2 * d2; res[4 * i + 2] = -d2;
                float d3 = q.w - res[4 * i + 3]; closs += d3 * d3; res[4 * i + 3] = -d3;
            }
            bis[r] = bi;
        }
        if (part == 0) {
            ids_out[(size_t)node * (L * RVQ) + layer * RVQ + 0] = (float)bis[0];
            ids_out[(size_t)node * (L * RVQ) + layer * RVQ + 1] = (float)bis[1];
            ids_out[(size_t)node * (L * RVQ) + layer * RVQ + 2] = (float)bis[2];
        }
    }

    closs = waveSum(closs);
    if (lane == 0) sred[wid] = closs;
    __syncthreads();
    if (t == 0) {
        float tot = (sred[0] + sred[1]) + (sred[2] + sred[3]);
        atomicAdd(commit, tot * (COMMIT_W / (float)(NN * D)));
    }
}

// ---------------- Heads ----------------
__global__ __launch_bounds__(256, 2) void k_head(
    const float* __restrict__ x_local,
    const float* __restrict__ Wp, const float* __restrict__ bp,
    const float* __restrict__ Wg, const float* __restrict__ bg,
    float* __restrict__ pred, float* __restrict__ gnn) {
    int t = threadIdx.x, lane = t & 63, wid = t >> 6;
    int jsafe = (lane < 9) ? lane : 0;

    float wp[D], wg[D];
    #pragma unroll
    for (int k = 0; k < D; ++k) {
        wp[k] = Wp[k * D + lane];
        wg[k] = Wg[k * 9 + jsafe];
    }
    float bpv = bp[lane], bgv = bg[jsafe];

    int w = blockIdx.x * 4 + wid;
    int wstep = gridDim.x * 4;
    for (int n = w; n < NN; n += wstep) {
        int nu = __builtin_amdgcn_readfirstlane(n);
        const float4* xrow = (const float4*)(x_local + (size_t)nu * D);
        float p = 0.f, g = 0.f;
        #pragma unroll
        for (int j = 0; j < 16; ++j) {
            float4 x4 = xrow[j];
            p += x4.x * wp[4 * j + 0]; g += x4.x * wg[4 * j + 0];
            p += x4.y * wp[4 * j + 1]; g += x4.y * wg[4 * j + 1];
            p += x4.z * wp[4 * j + 2]; g += x4.z * wg[4 * j + 2];
            p += x4.w * wp[4 * j + 3]; g += x4.w * wg[4 * j + 3];
        }
        pred[(size_t)n * D + lane] = p + bpv;
        if (lane < 9) gnn[(size_t)n * 9 + lane] = g + bgv;
    }
}

extern "C" void kernel_launch(void* const* d_in, const int* in_sizes, int n_in,
                              void* d_out, int out_size, void* d_ws, size_t ws_size,
                              hipStream_t stream) {
    const float* x   = (const float*)d_in[0];
    const int* ei    = (const int*)d_in[1];
    const float* Wa  = (const float*)d_in[2];
    const float* ba  = (const float*)d_in[3];
    const float* Wr  = (const float*)d_in[4];
    const float* Wl  = (const float*)d_in[5];
    const float* bl  = (const float*)d_in[6];
    const float* gamma = (const float*)d_in[7];
    const float* beta  = (const float*)d_in[8];
    const float* cbs = (const float*)d_in[9];
    const float* Wp  = (const float*)d_in[10];
    const float* bp  = (const float*)d_in[11];
    const float* Wg  = (const float*)d_in[12];
    const float* bg  = (const float*)d_in[13];

    const int* src = ei;
    const int* dst = ei + NE;

    int*   ws_i  = (int*)d_ws;
    float* ws_f  = (float*)d_ws;
    int* rowptr  = ws_i + OFS_ROWPTR;
    int* cnt     = ws_i + OFS_CNT;
    int* cursor  = ws_i + OFS_CURSOR;
    int* bsums   = ws_i + OFS_BSUMS;
    int* boffs   = ws_i + OFS_BOFFS;
    float* stats = ws_f + OFS_STATS;
    int* csr_src = ws_i + OFS_CSR;
    float* hA    = ws_f + OFS_HA;
    float* hB    = ws_f + OFS_HB;
    float* xloc  = ws_f + OFS_XLOC;
    float* part  = ws_f + OFS_PART;

    float* out    = (float*)d_out;
    float* pred   = out + OUT_PRED;
    float* commit = out + OUT_COMMIT;
    float* ids    = out + OUT_IDS;
    float* gnn    = out + OUT_GNN;

    // mean buffer: reuse the pred region of d_out as scratch during the
    // layer loop (k_head fully overwrites it at the end).
    float* meanb = pred;

    hipMemsetAsync(cnt, 0, NN * sizeof(int), stream);
    hipMemsetAsync(commit, 0, sizeof(float), stream);

    // CSR build
    k_count<<<(NE + 255) / 256, 256, 0, stream>>>(dst, cnt);
    int nscan = (NN + SCAN_B - 1) / SCAN_B;  // 98
    k_scan1<<<nscan, SCAN_B, 0, stream>>>(cnt, rowptr, bsums);
    k_scan2<<<1, SCAN_B, 0, stream>>>(bsums, boffs, nscan);
    k_scan3<<<nscan, SCAN_B, 0, stream>>>(rowptr, boffs);
    k_cursor<<<(NN + 1023) / 1024, 1024, 0, stream>>>(rowptr, cursor);
    k_fill<<<(NE + 255) / 256, 256, 0, stream>>>(src, dst, cursor, csr_src);
    k_sortrows<<<(NN + 255) / 256, 256, 0, stream>>>(rowptr, csr_src);

    // layers
    const float* hin = x;
    float* bufs[2] = {hA, hB};
    const int nblk_mv = NN / 32;              // 3125 blocks, 8 nodes/wave
    const int nblk_b  = (NN * 4 + 255) / 256; // 1563 blocks, one node per quad
    for (int i = 0; i < L; ++i) {
        float* hout = bufs[i & 1];
        k_gather<<<(NN + 3) / 4, 256, 0, stream>>>(hin, rowptr, csr_src, meanb);
        k_matvec<<<nblk_mv, 256, 0, stream>>>(meanb, hin, hout,
                                              Wa + i * D * D, ba + i * D,
                                              Wr + i * D * D, Wl + i * D * D, bl + i * D);
        k_bnstats<<<GRID_A, 256, 0, stream>>>(hout, part);
        k_red_stats<<<128, 256, 0, stream>>>(part, stats + i * 128);
        k_layer_b<<<nblk_b, 256, 0, stream>>>(hout, stats + i * 128,
                                              gamma + i * D, beta + i * D,
                                              cbs + i * RVQ * CODES * D,
                                              xloc, ids, i, commit, (i == 0) ? 1 : 0);
        hin = hout;
    }

    // heads
    k_head<<<2048, 256, 0, stream>>>(xloc, Wp, bp, Wg, bg, pred, gnn);
}

// Round 6
// 831.843 us; speedup vs baseline: 1.1842x; 1.1842x over previous
//
#include <hip/hip_runtime.h>
#include <math.h>

#define NN 100000
#define NE 1000000
#define D 64
#define L 3
#define RVQ 3
#define CODES 16
#define BN_EPS 1e-5f
#define COMMIT_W 0.25f

#define GRID_A 2048   // blocks for bnstats kernel (fixed: partials + node mapping)

// ---------------- ws layout (in 4-byte units) ----------------
#define OFS_ROWPTR 0           // 100001 ints
#define OFS_CNT    100016      // 100000 ints
#define OFS_CURSOR 200032      // 100000 ints
#define OFS_BSUMS  300048      // 128 ints
#define OFS_BOFFS  300176      // 128 ints
#define OFS_STATS  300304      // 3*128 floats (sum[64],sumsq[64] per layer)
#define OFS_CSR    300800      // 1000000 ints
#define OFS_HA     1300800     // 6400000 floats
#define OFS_HB     7700800     // 6400000 floats
#define OFS_XLOC   14100800    // 6400000 floats
#define OFS_PART   20500800    // 2048*128 floats = 262144
// total = 20,762,944 * 4 B ~= 83 MB
// NOTE: the mean buffer lives in d_out's pred region (scratch until k_head
// overwrites it at the very end).

// ---------------- d_out layout (floats) ----------------
#define OUT_PRED   0
#define OUT_COMMIT (NN * D)                       // 6,400,000
#define OUT_IDS    (NN * D + 1)                   // 6,400,001
#define OUT_GNN    (NN * D + 1 + NN * (L * RVQ))  // 7,300,001

static __device__ __forceinline__ float waveSum(float v) {
    #pragma unroll
    for (int off = 32; off; off >>= 1) v += __shfl_xor(v, off, 64);
    return v;
}

// DPP quad-permute helpers: value from lane^1 / lane^2 within each quad.
static __device__ __forceinline__ float qxor1(float v) {
    return __int_as_float(__builtin_amdgcn_mov_dpp(__float_as_int(v), 0xB1, 0xF, 0xF, 1));
}
static __device__ __forceinline__ float qxor2(float v) {
    return __int_as_float(__builtin_amdgcn_mov_dpp(__float_as_int(v), 0x4E, 0xF, 0xF, 1));
}

// ---------------- CSR build ----------------
__global__ void k_count(const int* __restrict__ dst, int* __restrict__ cnt) {
    int e = blockIdx.x * blockDim.x + threadIdx.x;
    if (e < NE) atomicAdd(&cnt[dst[e]], 1);
}

#define SCAN_B 1024
__global__ void k_scan1(const int* __restrict__ cnt, int* __restrict__ rowptr,
                        int* __restrict__ bsums) {
    __shared__ int sm[SCAN_B];
    int t = threadIdx.x;
    int i = blockIdx.x * SCAN_B + t;
    int v = (i < NN) ? cnt[i] : 0;
    sm[t] = v;
    __syncthreads();
    for (int off = 1; off < SCAN_B; off <<= 1) {
        int add = (t >= off) ? sm[t - off] : 0;
        __syncthreads();
        sm[t] += add;
        __syncthreads();
    }
    if (i < NN) rowptr[i + 1] = sm[t];
    if (t == SCAN_B - 1) bsums[blockIdx.x] = sm[t];
}

__global__ void k_scan2(const int* __restrict__ bsums, int* __restrict__ boffs, int nb) {
    __shared__ int sm[SCAN_B];
    int t = threadIdx.x;
    int orig = (t < nb) ? bsums[t] : 0;
    sm[t] = orig;
    __syncthreads();
    for (int off = 1; off < SCAN_B; off <<= 1) {
        int add = (t >= off) ? sm[t - off] : 0;
        __syncthreads();
        sm[t] += add;
        __syncthreads();
    }
    if (t < nb) boffs[t] = sm[t] - orig;  // exclusive
}

__global__ void k_scan3(int* __restrict__ rowptr, const int* __restrict__ boffs) {
    int i = blockIdx.x * SCAN_B + threadIdx.x;
    if (i < NN) rowptr[i + 1] += boffs[blockIdx.x];
    if (i == 0) rowptr[0] = 0;
}

__global__ void k_cursor(const int* __restrict__ rowptr, int* __restrict__ cursor) {
    int i = blockIdx.x * blockDim.x + threadIdx.x;
    if (i < NN) cursor[i] = rowptr[i];
}

__global__ void k_fill(const int* __restrict__ src, const int* __restrict__ dst,
                       int* __restrict__ cursor, int* __restrict__ csr_src) {
    int e = blockIdx.x * blockDim.x + threadIdx.x;
    if (e < NE) {
        int p = atomicAdd(&cursor[dst[e]], 1);
        csr_src[p] = src[e];
    }
}

// Canonicalize row order so the neighbor-sum order is deterministic.
__global__ void k_sortrows(const int* __restrict__ rowptr, int* __restrict__ csr) {
    int n = blockIdx.x * blockDim.x + threadIdx.x;
    if (n >= NN) return;
    int r0 = rowptr[n], r1 = rowptr[n + 1];
    for (int i = r0 + 1; i < r1; ++i) {
        int v = csr[i];
        int j = i - 1;
        while (j >= r0 && csr[j] > v) { csr[j + 1] = csr[j]; --j; }
        csr[j + 1] = v;
    }
}

// ---------------- Gather: mean of neighbor rows -> mean_out ----------------
__global__ __launch_bounds__(256) void k_gather(
    const float* __restrict__ h, const int* __restrict__ rowptr,
    const int* __restrict__ csr_src, float* __restrict__ mean_out) {
    int t = threadIdx.x;
    int lane = t & 63, wid = t >> 6;
    int n = blockIdx.x * 4 + wid;
    if (n >= NN) return;

    int r0 = rowptr[n], r1 = rowptr[n + 1];
    float s = 0.f;
    for (int base = r0; base < r1; base += 64) {
        int last = r1 - 1;
        int ii = base + lane;
        int idx = csr_src[(ii <= last) ? ii : last];  // coalesced, clamped
        int m = r1 - base;
        if (m > 64) m = 64;
        int j = 0;
        for (; j + 8 <= m; j += 8) {
            int i0 = __shfl(idx, j + 0, 64), i1 = __shfl(idx, j + 1, 64);
            int i2 = __shfl(idx, j + 2, 64), i3 = __shfl(idx, j + 3, 64);
            int i4 = __shfl(idx, j + 4, 64), i5 = __shfl(idx, j + 5, 64);
            int i6 = __shfl(idx, j + 6, 64), i7 = __shfl(idx, j + 7, 64);
            float v0 = h[i0 * D + lane], v1 = h[i1 * D + lane];
            float v2 = h[i2 * D + lane], v3 = h[i3 * D + lane];
            float v4 = h[i4 * D + lane], v5 = h[i5 * D + lane];
            float v6 = h[i6 * D + lane], v7 = h[i7 * D + lane];
            s += v0; s += v1; s += v2; s += v3;
            s += v4; s += v5; s += v6; s += v7;
        }
        for (; j + 4 <= m; j += 4) {
            int i0 = __shfl(idx, j + 0, 64), i1 = __shfl(idx, j + 1, 64);
            int i2 = __shfl(idx, j + 2, 64), i3 = __shfl(idx, j + 3, 64);
            float v0 = h[i0 * D + lane], v1 = h[i1 * D + lane];
            float v2 = h[i2 * D + lane], v3 = h[i3 * D + lane];
            s += v0; s += v1; s += v2; s += v3;
        }
        for (; j < m; ++j) {
            int i0 = __shfl(idx, j, 64);
            s += h[i0 * D + lane];
        }
    }
    float deg = (float)(r1 - r0);
    mean_out[n * D + lane] = s / fmaxf(deg, 1.0f);
}

// ---------------- Matvec: SAGE transform + skip linear ----------------
// R4 structure (16 nodes/wave, act broadcast via same-address ds_read_b128,
// weights global->VGPR) with the spill fixed: K-chunks of 8 keep only
// 24 weight floats live (vs 16-chunk's 48), so live set = 48 accs + 24 w +
// misc ~ 85 < the ~half-cap the allocator actually grants ((256,2) -> cap
// 256, expect ~100-128). R4 (VGPR=84, need ~100) and R5 (VGPR=64, need
// ~72) both spilled the weight arrays -> 75/33 MB of scratch HBM writes
// and 6x VALU inflation; WRITE_SIZE ~27 MB is the verification counter.
// Budget/CU: FMA 15.6us, weight L2 ~9us (16-node amortization), DS
// broadcasts 5.2us, all overlapping. FMA chains keep per-k {am,rm,lm}
// ascending-k order -> hp BIT-IDENTICAL to all previous passing kernels.
__global__ __launch_bounds__(256, 2) void k_matvec(
    const float* __restrict__ mean, const float* __restrict__ h,
    float* __restrict__ hp,
    const float* __restrict__ Wa, const float* __restrict__ ba,
    const float* __restrict__ Wr, const float* __restrict__ Wl,
    const float* __restrict__ bl) {
    __shared__ alignas(16) float lbuf[4][16][128]; // [wave][node][mean|h] = 32 KB
    int t = threadIdx.x, lane = t & 63, wid = t >> 6;

    int tb = (blockIdx.x * 4 + wid) * 16;   // first node of this wave's tile
    if (tb >= NN) return;                   // NN % 16 == 0: live tiles are full

    float bav = ba[lane], blv = bl[lane];

    // ---- stage 16 mean rows + 16 h rows into wave-private LDS (coalesced)
    {
        const float4* gm = (const float4*)(mean + (size_t)tb * D);
        const float4* gh = (const float4*)(h    + (size_t)tb * D);
        #pragma unroll
        for (int s = 0; s < 4; ++s) {
            int fid = s * 64 + lane;        // 0..255 float4 slots
            int node = fid >> 4, j = fid & 15;
            float4 vm = gm[fid];
            float4 vh = gh[fid];
            *(float4*)&lbuf[wid][node][4 * j]      = vm;
            *(float4*)&lbuf[wid][node][64 + 4 * j] = vh;
        }
    }
    // wave-private buffer: no barrier needed; compiler orders via lgkmcnt.

    float am[16], rm[16], lm[16];
    #pragma unroll
    for (int i = 0; i < 16; ++i) { am[i] = 0.f; rm[i] = 0.f; lm[i] = 0.f; }

    for (int c = 0; c < 8; ++c) {           // K chunks of 8 (keeps regs low)
        // chunk weights from global: 24 coalesced dword loads (VMEM pipe)
        float wa8[8], wr8[8], wl8[8];
        #pragma unroll
        for (int j = 0; j < 8; ++j) {
            wa8[j] = Wa[(c * 8 + j) * D + lane];
            wr8[j] = Wr[(c * 8 + j) * D + lane];
            wl8[j] = Wl[(c * 8 + j) * D + lane];
        }
        #pragma unroll
        for (int i = 0; i < 16; ++i) {
            const float* mb = &lbuf[wid][i][c * 8];
            const float* hb = &lbuf[wid][i][64 + c * 8];
            #pragma unroll
            for (int qq = 0; qq < 2; ++qq) {
                float4 m4 = *(const float4*)(mb + 4 * qq);  // broadcast b128
                float4 h4 = *(const float4*)(hb + 4 * qq);
                am[i] += m4.x * wa8[4 * qq + 0];
                rm[i] += h4.x * wr8[4 * qq + 0];
                lm[i] += h4.x * wl8[4 * qq + 0];
                am[i] += m4.y * wa8[4 * qq + 1];
                rm[i] += h4.y * wr8[4 * qq + 1];
                lm[i] += h4.y * wl8[4 * qq + 1];
                am[i] += m4.z * wa8[4 * qq + 2];
                rm[i] += h4.z * wr8[4 * qq + 2];
                lm[i] += h4.z * wl8[4 * qq + 2];
                am[i] += m4.w * wa8[4 * qq + 3];
                rm[i] += h4.w * wr8[4 * qq + 3];
                lm[i] += h4.w * wl8[4 * qq + 3];
            }
        }
    }

    #pragma unroll
    for (int i = 0; i < 16; ++i) {
        float sage = am[i] + bav + rm[i];
        float ss = waveSum(sage * sage);
        float inv = 1.0f / (sqrtf(ss) + 1e-12f);
        float hpv = sage * inv + lm[i] + blv;
        hp[(size_t)(tb + i) * D + lane] = hpv;
    }
}

// BN stat partials over the finished hp buffer. Replicates the ORIGINAL
// k_matvec accumulation order exactly -> stats BIT-IDENTICAL.
__global__ __launch_bounds__(256) void k_bnstats(
    const float* __restrict__ hp, float* __restrict__ partials) {
    __shared__ float red[2][4][D];
    int t = threadIdx.x, lane = t & 63, wid = t >> 6;
    int wg = blockIdx.x * 4 + wid;
    const int wstep = GRID_A * 4;
    float accS = 0.f, accQ = 0.f;
    for (int n = wg; n < NN; n += wstep) {
        float hpv = hp[(size_t)n * D + lane];
        accS += hpv;
        accQ += hpv * hpv;
    }
    red[0][wid][lane] = accS;
    red[1][wid][lane] = accQ;
    __syncthreads();
    if (wid == 0) {
        float s0 = (red[0][0][lane] + red[0][1][lane]) + (red[0][2][lane] + red[0][3][lane]);
        float q0 = (red[1][0][lane] + red[1][1][lane]) + (red[1][2][lane] + red[1][3][lane]);
        partials[blockIdx.x * 128 + lane]      = s0;
        partials[blockIdx.x * 128 + 64 + lane] = q0;
    }
}

// Parallel deterministic reduction of BN stat partials.
__global__ __launch_bounds__(256) void k_red_stats(
    const float* __restrict__ part, float* __restrict__ stats) {
    __shared__ float sm[256];
    int c = blockIdx.x;      // 0..127
    int i = threadIdx.x;     // 0..255
    float s = 0.f;
    #pragma unroll
    for (int k = 0; k < 8; ++k)
        s += part[(size_t)(i * 8 + k) * 128 + c];
    sm[i] = s;
    __syncthreads();
    #pragma unroll
    for (int off = 128; off >= 1; off >>= 1) {
        if (i < off) sm[i] += sm[i + off];
        __syncthreads();
    }
    if (i == 0) stats[c] = sm[0];
}

// ---------------- Layer part B: BN + ReLU + x_local accumulate + residual VQ
// Quad-per-node scheme: residual in registers, DPP quad reduces, serial
// first-max argmax; bit-identical sims to the wave-per-node original.
#define CBSTRIDE 68
__global__ __launch_bounds__(256) void k_layer_b(
    float* __restrict__ hp,              // in: pre-BN h'; out: post-ReLU h
    const float* __restrict__ stats,
    const float* __restrict__ gamma, const float* __restrict__ beta,
    const float* __restrict__ cbs,       // [RVQ][CODES][D] for this layer
    float* __restrict__ x_local,
    float* __restrict__ ids_out,         // [NN][L*RVQ] region base
    int layer, float* __restrict__ commit, int first_layer) {
    __shared__ alignas(16) float scb[RVQ * CODES * CBSTRIDE];
    __shared__ alignas(16) float sscale[D];
    __shared__ alignas(16) float sshift[D];
    __shared__ float sred[4];
    int t = threadIdx.x, lane = t & 63, wid = t >> 6;

    // normalize codebook rows into LDS (identical math to before)
    for (int row = wid; row < RVQ * CODES; row += 4) {
        float v = cbs[row * D + lane];
        float ss = waveSum(v * v);
        scb[row * CBSTRIDE + lane] = v / (sqrtf(ss) + 1e-12f);
    }
    // BN scale/shift per channel
    if (t < D) {
        float mu = stats[t] * (1.0f / NN);
        float var = stats[64 + t] * (1.0f / NN) - mu * mu;
        float scale = rsqrtf(var + BN_EPS) * gamma[t];
        sscale[t] = scale;
        sshift[t] = beta[t] - mu * scale;
    }
    __syncthreads();

    int gid = blockIdx.x * 256 + t;
    int node = gid >> 2;      // one node per quad of lanes
    int part = t & 3;         // which 16-channel slice this lane owns
    float closs = 0.f;

    if (node < NN) {
        float res[16];
        size_t base = (size_t)node * D + part * 16;
        const float4* hr = (const float4*)(hp + base);
        float4* hw = (float4*)(hp + base);
        float4* xw = (float4*)(x_local + base);
        const float4* scp = (const float4*)(sscale + part * 16);
        const float4* shp = (const float4*)(sshift + part * 16);

        #pragma unroll
        for (int i = 0; i < 4; ++i) {
            float4 v = hr[i];
            float4 sc = scp[i], sh = shp[i];
            float4 hn;
            hn.x = fmaxf(v.x * sc.x + sh.x, 0.f);
            hn.y = fmaxf(v.y * sc.y + sh.y, 0.f);
            hn.z = fmaxf(v.z * sc.z + sh.z, 0.f);
            hn.w = fmaxf(v.w * sc.w + sh.w, 0.f);
            hw[i] = hn;
            if (first_layer) {
                xw[i] = hn;
            } else {
                float4 xl = xw[i];
                xl.x += hn.x; xl.y += hn.y; xl.z += hn.z; xl.w += hn.w;
                xw[i] = xl;
            }
            res[4 * i + 0] = hn.x; res[4 * i + 1] = hn.y;
            res[4 * i + 2] = hn.z; res[4 * i + 3] = hn.w;
        }

        int bis[RVQ];
        #pragma unroll
        for (int r = 0; r < RVQ; ++r) {
            float sims[CODES];
            #pragma unroll
            for (int j = 0; j < CODES; ++j) {
                const float* cr = &scb[(r * CODES + j) * CBSTRIDE + part * 16];
                float4 c0 = *(const float4*)(cr + 0);
                float4 c1 = *(const float4*)(cr + 4);
                float4 c2 = *(const float4*)(cr + 8);
                float4 c3 = *(const float4*)(cr + 12);
                float a = res[0] * c0.x;
                a += res[1] * c0.y;  a += res[2] * c0.z;  a += res[3] * c0.w;
                a += res[4] * c1.x;  a += res[5] * c1.y;  a += res[6] * c1.z;  a += res[7] * c1.w;
                a += res[8] * c2.x;  a += res[9] * c2.y;  a += res[10] * c2.z; a += res[11] * c2.w;
                a += res[12] * c3.x; a += res[13] * c3.y; a += res[14] * c3.z; a += res[15] * c3.w;
                float b = a + qxor1(a);
                sims[j] = b + qxor2(b);
            }
            float bv = sims[0];
            int bi = 0;
            #pragma unroll
            for (int j = 1; j < CODES; ++j)
                if (sims[j] > bv) { bv = sims[j]; bi = j; }

            const float* qr = &scb[(r * CODES + bi) * CBSTRIDE + part * 16];
            #pragma unroll
            for (int i = 0; i < 4; ++i) {
                float4 q = *(const float4*)(qr + 4 * i);
                float d0 = q.x - res[4 * i + 0]; closs += d0 * d0; res[4 * i + 0] = -d0;
                float d1 = q.y - res[4 * i + 1]; closs += d1 * d1; res[4 * i + 1] = -d1;
                float d2 = q.z - res[4 * i + 2]; closs += d2 * d2; res[4 * i + 2] = -d2;
                float d3 = q.w - res[4 * i + 3]; closs += d3 * d3; res[4 * i + 3] = -d3;
            }
            bis[r] = bi;
        }
        if (part == 0) {
            ids_out[(size_t)node * (L * RVQ) + layer * RVQ + 0] = (float)bis[0];
            ids_out[(size_t)node * (L * RVQ) + layer * RVQ + 1] = (float)bis[1];
            ids_out[(size_t)node * (L * RVQ) + layer * RVQ + 2] = (float)bis[2];
        }
    }

    closs = waveSum(closs);
    if (lane == 0) sred[wid] = closs;
    __syncthreads();
    if (t == 0) {
        float tot = (sred[0] + sred[1]) + (sred[2] + sred[3]);
        atomicAdd(commit, tot * (COMMIT_W / (float)(NN * D)));
    }
}

// ---------------- Heads ----------------
__global__ __launch_bounds__(256, 2) void k_head(
    const float* __restrict__ x_local,
    const float* __restrict__ Wp, const float* __restrict__ bp,
    const float* __restrict__ Wg, const float* __restrict__ bg,
    float* __restrict__ pred, float* __restrict__ gnn) {
    int t = threadIdx.x, lane = t & 63, wid = t >> 6;
    int jsafe = (lane < 9) ? lane : 0;

    float wp[D], wg[D];
    #pragma unroll
    for (int k = 0; k < D; ++k) {
        wp[k] = Wp[k * D + lane];
        wg[k] = Wg[k * 9 + jsafe];
    }
    float bpv = bp[lane], bgv = bg[jsafe];

    int w = blockIdx.x * 4 + wid;
    int wstep = gridDim.x * 4;
    for (int n = w; n < NN; n += wstep) {
        int nu = __builtin_amdgcn_readfirstlane(n);
        const float4* xrow = (const float4*)(x_local + (size_t)nu * D);
        float p = 0.f, g = 0.f;
        #pragma unroll
        for (int j = 0; j < 16; ++j) {
            float4 x4 = xrow[j];
            p += x4.x * wp[4 * j + 0]; g += x4.x * wg[4 * j + 0];
            p += x4.y * wp[4 * j + 1]; g += x4.y * wg[4 * j + 1];
            p += x4.z * wp[4 * j + 2]; g += x4.z * wg[4 * j + 2];
            p += x4.w * wp[4 * j + 3]; g += x4.w * wg[4 * j + 3];
        }
        pred[(size_t)n * D + lane] = p + bpv;
        if (lane < 9) gnn[(size_t)n * 9 + lane] = g + bgv;
    }
}

extern "C" void kernel_launch(void* const* d_in, const int* in_sizes, int n_in,
                              void* d_out, int out_size, void* d_ws, size_t ws_size,
                              hipStream_t stream) {
    const float* x   = (const float*)d_in[0];
    const int* ei    = (const int*)d_in[1];
    const float* Wa  = (const float*)d_in[2];
    const float* ba  = (const float*)d_in[3];
    const float* Wr  = (const float*)d_in[4];
    const float* Wl  = (const float*)d_in[5];
    const float* bl  = (const float*)d_in[6];
    const float* gamma = (const float*)d_in[7];
    const float* beta  = (const float*)d_in[8];
    const float* cbs = (const float*)d_in[9];
    const float* Wp  = (const float*)d_in[10];
    const float* bp  = (const float*)d_in[11];
    const float* Wg  = (const float*)d_in[12];
    const float* bg  = (const float*)d_in[13];

    const int* src = ei;
    const int* dst = ei + NE;

    int*   ws_i  = (int*)d_ws;
    float* ws_f  = (float*)d_ws;
    int* rowptr  = ws_i + OFS_ROWPTR;
    int* cnt     = ws_i + OFS_CNT;
    int* cursor  = ws_i + OFS_CURSOR;
    int* bsums   = ws_i + OFS_BSUMS;
    int* boffs   = ws_i + OFS_BOFFS;
    float* stats = ws_f + OFS_STATS;
    int* csr_src = ws_i + OFS_CSR;
    float* hA    = ws_f + OFS_HA;
    float* hB    = ws_f + OFS_HB;
    float* xloc  = ws_f + OFS_XLOC;
    float* part  = ws_f + OFS_PART;

    float* out    = (float*)d_out;
    float* pred   = out + OUT_PRED;
    float* commit = out + OUT_COMMIT;
    float* ids    = out + OUT_IDS;
    float* gnn    = out + OUT_GNN;

    // mean buffer: reuse the pred region of d_out as scratch during the
    // layer loop (k_head fully overwrites it at the end).
    float* meanb = pred;

    hipMemsetAsync(cnt, 0, NN * sizeof(int), stream);
    hipMemsetAsync(commit, 0, sizeof(float), stream);

    // CSR build
    k_count<<<(NE + 255) / 256, 256, 0, stream>>>(dst, cnt);
    int nscan = (NN + SCAN_B - 1) / SCAN_B;  // 98
    k_scan1<<<nscan, SCAN_B, 0, stream>>>(cnt, rowptr, bsums);
    k_scan2<<<1, SCAN_B, 0, stream>>>(bsums, boffs, nscan);
    k_scan3<<<nscan, SCAN_B, 0, stream>>>(rowptr, boffs);
    k_cursor<<<(NN + 1023) / 1024, 1024, 0, stream>>>(rowptr, cursor);
    k_fill<<<(NE + 255) / 256, 256, 0, stream>>>(src, dst, cursor, csr_src);
    k_sortrows<<<(NN + 255) / 256, 256, 0, stream>>>(rowptr, csr_src);

    // layers
    const float* hin = x;
    float* bufs[2] = {hA, hB};
    const int nblk_mv = (NN / 16 + 3) / 4;    // 1563 blocks, 16 nodes/wave
    const int nblk_b  = (NN * 4 + 255) / 256; // 1563 blocks, one node per quad
    for (int i = 0; i < L; ++i) {
        float* hout = bufs[i & 1];
        k_gather<<<(NN + 3) / 4, 256, 0, stream>>>(hin, rowptr, csr_src, meanb);
        k_matvec<<<nblk_mv, 256, 0, stream>>>(meanb, hin, hout,
                                              Wa + i * D * D, ba + i * D,
                                              Wr + i * D * D, Wl + i * D * D, bl + i * D);
        k_bnstats<<<GRID_A, 256, 0, stream>>>(hout, part);
        k_red_stats<<<128, 256, 0, stream>>>(part, stats + i * 128);
        k_layer_b<<<nblk_b, 256, 0, stream>>>(hout, stats + i * 128,
                                              gamma + i * D, beta + i * D,
                                              cbs + i * RVQ * CODES * D,
                                              xloc, ids, i, commit, (i == 0) ? 1 : 0);
        hin = hout;
    }

    // heads
    k_head<<<2048, 256, 0, stream>>>(xloc, Wp, bp, Wg, bg, pred, gnn);
}